// Round 6
// baseline (1956.391 us; speedup 1.0000x reference)
//
#include <hip/hip_runtime.h>
#include <hip/hip_bf16.h>
#include <cstdint>
#include <cstddef>

typedef __bf16 bf16_t;
typedef __attribute__((ext_vector_type(4))) __bf16 bf16x4;
typedef __attribute__((ext_vector_type(8))) __bf16 bf16x8;
typedef __attribute__((ext_vector_type(4))) float f32x4;

#define MFMA16(a, b, c) __builtin_amdgcn_mfma_f32_16x16x32_bf16(a, b, c, 0, 0, 0)

constexpr int LSEQ = 2048;
constexpr int DMODEL = 512;
constexpr int NHEAD = 8;
constexpr int DKH = 64;
constexpr float INV_TEMPER = 0.04419417382415922f;  // 1/sqrt(512)

// ------------------------------------------- transpose+cast W [K][N] f32 -> Wt [N][K] bf16
__global__ __launch_bounds__(256) void k_transpose_cast(const float* __restrict__ in,
                                                        bf16_t* __restrict__ out,
                                                        int K, int N) {
    __shared__ float tile[32][33];
    int n0 = blockIdx.x * 32, k0 = blockIdx.y * 32;
    int tx = threadIdx.x, ty = threadIdx.y;
#pragma unroll
    for (int i = 0; i < 4; i++)
        tile[ty + i * 8][tx] = in[(size_t)(k0 + ty + i * 8) * N + n0 + tx];
    __syncthreads();
#pragma unroll
    for (int i = 0; i < 4; i++)
        out[(size_t)(n0 + ty + i * 8) * K + k0 + tx] = (bf16_t)tile[tx][ty + i * 8];
}

// ------------------------------------------- NT GEMM: C[m][n] = A[m][:]·Bt[n][:] + bias
// MODE 0: A is f32 (cast to bf16 during staging); split q/k/v heads, Q scaled; bf16 out.
// MODE 1: A is bf16; f32 out (final projection).
template <int MODE>
__global__ __launch_bounds__(256) void k_gemm_nt(const void* __restrict__ Av,
                                                 const bf16_t* __restrict__ Bt,
                                                 const float* __restrict__ bias,
                                                 bf16_t* __restrict__ outQ,
                                                 bf16_t* __restrict__ outK,
                                                 bf16_t* __restrict__ outV,
                                                 float* __restrict__ outO, int K) {
    __shared__ bf16_t As[128 * 32];
    __shared__ bf16_t Bs[128 * 32];
    int t = threadIdx.x;
    int lane = t & 63, w = t >> 6;
    int wm = w >> 1, wn = w & 1;
    int rr = lane & 15, hq = lane >> 4;
    int m0 = blockIdx.x * 128, n0 = blockIdx.y * 128;
    int srow = t >> 2, sseg = t & 3;
    const float* gaF = (const float*)Av + (size_t)(m0 + srow) * K + sseg * 8;
    const bf16_t* gaB = (const bf16_t*)Av + (size_t)(m0 + srow) * K + sseg * 8;
    const bf16_t* gb = Bt + (size_t)(n0 + srow) * K + sseg * 8;
    f32x4 acc[4][4] = {};
    for (int k0 = 0; k0 < K; k0 += 32) {
        bf16x8 a0, a1;
        if (MODE == 0) {
            float4 l0 = *reinterpret_cast<const float4*>(gaF + k0);
            float4 h0 = *reinterpret_cast<const float4*>(gaF + k0 + 4);
            float4 l1 = *reinterpret_cast<const float4*>(gaF + (size_t)64 * K + k0);
            float4 h1 = *reinterpret_cast<const float4*>(gaF + (size_t)64 * K + k0 + 4);
            a0[0] = (bf16_t)l0.x; a0[1] = (bf16_t)l0.y; a0[2] = (bf16_t)l0.z; a0[3] = (bf16_t)l0.w;
            a0[4] = (bf16_t)h0.x; a0[5] = (bf16_t)h0.y; a0[6] = (bf16_t)h0.z; a0[7] = (bf16_t)h0.w;
            a1[0] = (bf16_t)l1.x; a1[1] = (bf16_t)l1.y; a1[2] = (bf16_t)l1.z; a1[3] = (bf16_t)l1.w;
            a1[4] = (bf16_t)h1.x; a1[5] = (bf16_t)h1.y; a1[6] = (bf16_t)h1.z; a1[7] = (bf16_t)h1.w;
        } else {
            a0 = *reinterpret_cast<const bf16x8*>(gaB + k0);
            a1 = *reinterpret_cast<const bf16x8*>(gaB + (size_t)64 * K + k0);
        }
        uint4 b0 = *reinterpret_cast<const uint4*>(gb + k0);
        uint4 b1 = *reinterpret_cast<const uint4*>(gb + (size_t)64 * K + k0);
        __syncthreads();
        *reinterpret_cast<bf16x8*>(&As[srow * 32 + sseg * 8]) = a0;
        *reinterpret_cast<bf16x8*>(&As[(srow + 64) * 32 + sseg * 8]) = a1;
        *reinterpret_cast<uint4*>(&Bs[srow * 32 + sseg * 8]) = b0;
        *reinterpret_cast<uint4*>(&Bs[(srow + 64) * 32 + sseg * 8]) = b1;
        __syncthreads();
        bf16x8 af[4], bff[4];
#pragma unroll
        for (int i = 0; i < 4; i++) {
            af[i] = *reinterpret_cast<const bf16x8*>(&As[(wm * 64 + i * 16 + rr) * 32 + hq * 8]);
            bff[i] = *reinterpret_cast<const bf16x8*>(&Bs[(wn * 64 + i * 16 + rr) * 32 + hq * 8]);
        }
#pragma unroll
        for (int mi = 0; mi < 4; mi++)
#pragma unroll
            for (int ni = 0; ni < 4; ni++)
                acc[mi][ni] = MFMA16(af[mi], bff[ni], acc[mi][ni]);
    }
    // epilogue (C/D layout: col = lane&15, row = 4*(lane>>4)+reg  [m89-verified])
#pragma unroll
    for (int mi = 0; mi < 4; mi++) {
#pragma unroll
        for (int ni = 0; ni < 4; ni++) {
            int gn = n0 + wn * 64 + ni * 16 + rr;
            float bv = bias[gn];
            int gmb = m0 + wm * 64 + mi * 16 + hq * 4;
            if (MODE == 0) {
                int which = gn >> 9;        // 0=q 1=k 2=v
                int hn = (gn >> 6) & 7;     // head
                int dk = gn & 63;
                bf16_t* dst = which == 0 ? outQ : (which == 1 ? outK : outV);
                float scale = which == 0 ? INV_TEMPER : 1.0f;
#pragma unroll
                for (int rg = 0; rg < 4; rg++) {
                    int gm = gmb + rg;
                    int bb = gm >> 11, ll = gm & 2047;
                    float v = (acc[mi][ni][rg] + bv) * scale;
                    dst[(((size_t)bb * NHEAD + hn) * LSEQ + ll) * DKH + dk] = (bf16_t)v;
                }
            } else {
#pragma unroll
                for (int rg = 0; rg < 4; rg++) {
                    int gm = gmb + rg;
                    outO[(size_t)gm * DMODEL + gn] = acc[mi][ni][rg] + bv;
                }
            }
        }
    }
}

// ------------------------------------------- BRUTE-FORCE attention (diagnosis round)
// Zero MFMA, zero fragment-layout assumptions. One block per (h, b, 16 q-rows).
// Thread (r, seg) owns row r, cols [seg*128, seg*128+128).
// S: bf16 [16][2048] in exactly 64 KiB LDS (row-XOR swizzle for bank spread).
// P stored PRE-NORMALIZED (bf16); attns written from normalized LDS values.
__global__ __launch_bounds__(256) void k_attn_bf(const bf16_t* __restrict__ Qh,
                                                 const bf16_t* __restrict__ Kh,
                                                 const bf16_t* __restrict__ Vh,
                                                 const int* __restrict__ mask,
                                                 float* __restrict__ attn_out,
                                                 bf16_t* __restrict__ Obf) {
    __shared__ unsigned short sU[32768];  // 65536 B == 64 KiB exactly
    char* sC = (char*)sU;
    float* sF = (float*)sU;
    int t = threadIdx.x;
    int bid = blockIdx.x;
    int h = bid & 7, b = (bid >> 3) & 1, qt = bid >> 4;
    int q0 = qt * 16;
    int bh = b * NHEAD + h;
    int r = t >> 4, seg = t & 15;
    auto swzb = [](int x) { return x ^ (((x >> 12) & 7) << 4); };

    // ---- phase 0: Q row r -> f32 registers (redundant across segs; L2-hot)
    float qf[64];
    {
        const bf16_t* qp = Qh + ((size_t)bh * LSEQ + q0 + r) * DKH;
#pragma unroll
        for (int dv = 0; dv < 8; dv++) {
            bf16x8 qv = *reinterpret_cast<const bf16x8*>(qp + dv * 8);
#pragma unroll
            for (int e = 0; e < 8; e++) qf[dv * 8 + e] = (float)qv[e];
        }
    }

    // ---- phase 1: scores + mask + exp + row-sum (f32 dot products)
    const bf16_t* kb = Kh + (size_t)bh * LSEQ * DKH;
    const int* mrow = mask + ((size_t)b * LSEQ + q0 + r) * LSEQ;
    float sum = 0.f;
    for (int jc = 0; jc < 128; jc++) {
        int c = seg * 128 + jc;
        const bf16_t* kp = kb + (size_t)c * DKH;
        float s = 0.f;
#pragma unroll
        for (int dv = 0; dv < 8; dv++) {
            bf16x8 kv = *reinterpret_cast<const bf16x8*>(kp + dv * 8);
#pragma unroll
            for (int e = 0; e < 8; e++) s += qf[dv * 8 + e] * (float)kv[e];
        }
        float p = mrow[c] ? 0.f : __expf(s);
        sum += p;
        *reinterpret_cast<bf16_t*>(sC + swzb(r * 4096 + c * 2)) = (bf16_t)p;
    }
    // width-16 reduce over segs (threads r*16..r*16+15 are 16 contiguous lanes)
    sum += __shfl_xor(sum, 8, 16);
    sum += __shfl_xor(sum, 4, 16);
    sum += __shfl_xor(sum, 2, 16);
    sum += __shfl_xor(sum, 1, 16);
    float inv = 1.0f / sum;

    // ---- phase 1b: normalize own cols in-place (bf16)
#pragma unroll
    for (int jj = 0; jj < 16; jj++) {
        int cb = seg * 128 + jj * 8;
        int sb = swzb(r * 4096 + cb * 2);
        bf16x8 pv = *reinterpret_cast<bf16x8*>(sC + sb);
        bf16x8 nv;
#pragma unroll
        for (int e = 0; e < 8; e++) nv[e] = (bf16_t)((float)pv[e] * inv);
        *reinterpret_cast<bf16x8*>(sC + sb) = nv;
    }
    __syncthreads();  // all P normalized before cross-thread reads

    // ---- phase 1c: attns write, coalesced (lane t writes cols 4t..4t+3 per row-chunk)
#pragma unroll 4
    for (int i = 0; i < 32; i++) {
        int e4 = (i * 256 + t) * 4;
        int rp = e4 >> 11, cp = e4 & 2047;
        bf16x4 pv = *reinterpret_cast<bf16x4*>(sC + swzb(rp * 4096 + cp * 2));
        float4 ov;
        ov.x = (float)pv[0]; ov.y = (float)pv[1]; ov.z = (float)pv[2]; ov.w = (float)pv[3];
        float* aout = attn_out + ((size_t)(h * 2 + b) * LSEQ + q0 + rp) * LSEQ + cp;
        *reinterpret_cast<float4*>(aout) = ov;
    }

    // ---- phase 2: PV (f32 FMA; P pre-normalized so no final scale)
    const bf16_t* vb = Vh + (size_t)bh * LSEQ * DKH;
    float o[64];
#pragma unroll
    for (int d = 0; d < 64; d++) o[d] = 0.f;
    for (int jc = 0; jc < 128; jc++) {
        int c = seg * 128 + jc;
        float pc = (float)*reinterpret_cast<bf16_t*>(sC + swzb(r * 4096 + c * 2));
        const bf16_t* vp = vb + (size_t)c * DKH;
#pragma unroll
        for (int dv = 0; dv < 8; dv++) {
            bf16x8 vv = *reinterpret_cast<const bf16x8*>(vp + dv * 8);
#pragma unroll
            for (int e = 0; e < 8; e++) o[dv * 8 + e] += pc * (float)vv[e];
        }
    }
    __syncthreads();  // all S reads done before overwrite with partials

    // ---- phase 3: per-seg partials -> LDS (16 rows x 16 segs x 64 d = 64 KiB), reduce
#pragma unroll
    for (int d = 0; d < 64; d++) sF[(r * 16 + seg) * 64 + d] = o[d];
    __syncthreads();
#pragma unroll
    for (int i = 0; i < 4; i++) {
        int e = i * 256 + t;
        int orow = e >> 6, oc = e & 63;
        float v = 0.f;
#pragma unroll
        for (int sg = 0; sg < 16; sg++) v += sF[(orow * 16 + sg) * 64 + oc];
        Obf[(((size_t)b * LSEQ + q0 + orow) * NHEAD + h) * DKH + oc] = (bf16_t)v;
    }
}

// ----------------------------------------------------------------------- launch
extern "C" void kernel_launch(void* const* d_in, const int* in_sizes, int n_in,
                              void* d_out, int out_size, void* d_ws, size_t ws_size,
                              hipStream_t stream) {
    (void)in_sizes; (void)n_in; (void)out_size; (void)ws_size;
    const float* q = (const float*)d_in[0];
    const int* mask = (const int*)d_in[3];
    const float* W_qkv = (const float*)d_in[4];
    const float* b_qkv = (const float*)d_in[5];
    const float* W_proj = (const float*)d_in[6];
    const float* b_proj = (const float*)d_in[7];
    float* out = (float*)d_out;
    float* attn_out = out + (size_t)2 * LSEQ * DMODEL;  // f32 elements

    char* ws = (char*)d_ws;
    bf16_t* wqkv_t = (bf16_t*)(ws);                   // 1.5 MB
    bf16_t* wproj_t = (bf16_t*)(ws + 1572864);        // 0.5 MB
    bf16_t* Qh = (bf16_t*)(ws + 2097152);             // 4 MB
    bf16_t* Kh = (bf16_t*)(ws + 6291456);             // 4 MB
    bf16_t* Vh = (bf16_t*)(ws + 10485760);            // 4 MB
    bf16_t* Obf = (bf16_t*)(ws + 14680064);           // 4 MB  (total 18 MB)

    k_transpose_cast<<<dim3(48, 16), dim3(32, 8), 0, stream>>>(W_qkv, wqkv_t, 512, 1536);
    k_transpose_cast<<<dim3(16, 16), dim3(32, 8), 0, stream>>>(W_proj, wproj_t, 512, 512);
    k_gemm_nt<0><<<dim3(32, 12), 256, 0, stream>>>(q, wqkv_t, b_qkv, Qh, Kh, Vh, nullptr, 512);
    k_attn_bf<<<2048, 256, 0, stream>>>(Qh, Kh, Vh, mask, attn_out, Obf);
    k_gemm_nt<1><<<dim3(32, 4), 256, 0, stream>>>(Obf, wproj_t, b_proj, nullptr, nullptr, nullptr, out, 512);
}

// Round 7
// 195.104 us; speedup vs baseline: 10.0274x; 10.0274x over previous
//
#include <hip/hip_runtime.h>
#include <hip/hip_bf16.h>
#include <cstdint>
#include <cstddef>

typedef __bf16 bf16_t;
typedef __attribute__((ext_vector_type(4))) __bf16 bf16x4;
typedef __attribute__((ext_vector_type(8))) __bf16 bf16x8;
typedef __attribute__((ext_vector_type(4))) float f32x4;

#define MFMA16(a, b, c) __builtin_amdgcn_mfma_f32_16x16x32_bf16(a, b, c, 0, 0, 0)

constexpr int LSEQ = 2048;
constexpr int DMODEL = 512;
constexpr int NHEAD = 8;
constexpr int DKH = 64;
constexpr float INV_TEMPER = 0.04419417382415922f;  // 1/sqrt(512)

// ------------------------------------------- transpose+cast W [K][N] f32 -> Wt [N][K] bf16
__global__ __launch_bounds__(256) void k_transpose_cast(const float* __restrict__ in,
                                                        bf16_t* __restrict__ out,
                                                        int K, int N) {
    __shared__ float tile[32][33];
    int n0 = blockIdx.x * 32, k0 = blockIdx.y * 32;
    int tx = threadIdx.x, ty = threadIdx.y;
#pragma unroll
    for (int i = 0; i < 4; i++)
        tile[ty + i * 8][tx] = in[(size_t)(k0 + ty + i * 8) * N + n0 + tx];
    __syncthreads();
#pragma unroll
    for (int i = 0; i < 4; i++)
        out[(size_t)(n0 + ty + i * 8) * K + k0 + tx] = (bf16_t)tile[tx][ty + i * 8];
}

// ------------------------------------------- NT GEMM: C[m][n] = A[m][:]·Bt[n][:] + bias
// MODE 0: A f32 (cast in staging); Q -> Qh (scaled), K -> Kh, V -> Vt[bh][dk][l]; bf16 out.
// MODE 1: A bf16; f32 out (final projection).
template <int MODE>
__global__ __launch_bounds__(256) void k_gemm_nt(const void* __restrict__ Av,
                                                 const bf16_t* __restrict__ Bt,
                                                 const float* __restrict__ bias,
                                                 bf16_t* __restrict__ outQ,
                                                 bf16_t* __restrict__ outK,
                                                 bf16_t* __restrict__ outV,
                                                 float* __restrict__ outO, int K) {
    __shared__ bf16_t As[128 * 32];
    __shared__ bf16_t Bs[128 * 32];
    int t = threadIdx.x;
    int lane = t & 63, w = t >> 6;
    int wm = w >> 1, wn = w & 1;
    int rr = lane & 15, hq = lane >> 4;
    int m0 = blockIdx.x * 128, n0 = blockIdx.y * 128;
    int srow = t >> 2, sseg = t & 3;
    const float* gaF = (const float*)Av + (size_t)(m0 + srow) * K + sseg * 8;
    const bf16_t* gaB = (const bf16_t*)Av + (size_t)(m0 + srow) * K + sseg * 8;
    const bf16_t* gb = Bt + (size_t)(n0 + srow) * K + sseg * 8;
    f32x4 acc[4][4] = {};
    for (int k0 = 0; k0 < K; k0 += 32) {
        bf16x8 a0, a1;
        if (MODE == 0) {
            float4 l0 = *reinterpret_cast<const float4*>(gaF + k0);
            float4 h0 = *reinterpret_cast<const float4*>(gaF + k0 + 4);
            float4 l1 = *reinterpret_cast<const float4*>(gaF + (size_t)64 * K + k0);
            float4 h1 = *reinterpret_cast<const float4*>(gaF + (size_t)64 * K + k0 + 4);
            a0[0] = (bf16_t)l0.x; a0[1] = (bf16_t)l0.y; a0[2] = (bf16_t)l0.z; a0[3] = (bf16_t)l0.w;
            a0[4] = (bf16_t)h0.x; a0[5] = (bf16_t)h0.y; a0[6] = (bf16_t)h0.z; a0[7] = (bf16_t)h0.w;
            a1[0] = (bf16_t)l1.x; a1[1] = (bf16_t)l1.y; a1[2] = (bf16_t)l1.z; a1[3] = (bf16_t)l1.w;
            a1[4] = (bf16_t)h1.x; a1[5] = (bf16_t)h1.y; a1[6] = (bf16_t)h1.z; a1[7] = (bf16_t)h1.w;
        } else {
            a0 = *reinterpret_cast<const bf16x8*>(gaB + k0);
            a1 = *reinterpret_cast<const bf16x8*>(gaB + (size_t)64 * K + k0);
        }
        uint4 b0 = *reinterpret_cast<const uint4*>(gb + k0);
        uint4 b1 = *reinterpret_cast<const uint4*>(gb + (size_t)64 * K + k0);
        __syncthreads();
        *reinterpret_cast<bf16x8*>(&As[srow * 32 + sseg * 8]) = a0;
        *reinterpret_cast<bf16x8*>(&As[(srow + 64) * 32 + sseg * 8]) = a1;
        *reinterpret_cast<uint4*>(&Bs[srow * 32 + sseg * 8]) = b0;
        *reinterpret_cast<uint4*>(&Bs[(srow + 64) * 32 + sseg * 8]) = b1;
        __syncthreads();
        bf16x8 af[4], bff[4];
#pragma unroll
        for (int i = 0; i < 4; i++) {
            af[i] = *reinterpret_cast<const bf16x8*>(&As[(wm * 64 + i * 16 + rr) * 32 + hq * 8]);
            bff[i] = *reinterpret_cast<const bf16x8*>(&Bs[(wn * 64 + i * 16 + rr) * 32 + hq * 8]);
        }
#pragma unroll
        for (int mi = 0; mi < 4; mi++)
#pragma unroll
            for (int ni = 0; ni < 4; ni++)
                acc[mi][ni] = MFMA16(af[mi], bff[ni], acc[mi][ni]);
    }
    // epilogue (C/D layout: col = lane&15, row = 4*(lane>>4)+reg  [verified in-harness r6])
#pragma unroll
    for (int mi = 0; mi < 4; mi++) {
#pragma unroll
        for (int ni = 0; ni < 4; ni++) {
            int gn = n0 + wn * 64 + ni * 16 + rr;
            float bv = bias[gn];
            int gmb = m0 + wm * 64 + mi * 16 + hq * 4;
            if (MODE == 0) {
                int which = gn >> 9;        // 0=q 1=k 2=v
                int hn = (gn >> 6) & 7;     // head
                int dk = gn & 63;
                if (which == 2) {
                    // V -> Vt[bh][dk][l]  (transposed store; replaces k_transpose_v)
#pragma unroll
                    for (int rg = 0; rg < 4; rg++) {
                        int gm = gmb + rg;
                        int bb = gm >> 11, ll = gm & 2047;
                        outV[(((size_t)bb * NHEAD + hn) * DKH + dk) * LSEQ + ll] =
                            (bf16_t)(acc[mi][ni][rg] + bv);
                    }
                } else {
                    bf16_t* dst = which == 0 ? outQ : outK;
                    float scale = which == 0 ? INV_TEMPER : 1.0f;
#pragma unroll
                    for (int rg = 0; rg < 4; rg++) {
                        int gm = gmb + rg;
                        int bb = gm >> 11, ll = gm & 2047;
                        float v = (acc[mi][ni][rg] + bv) * scale;
                        dst[(((size_t)bb * NHEAD + hn) * LSEQ + ll) * DKH + dk] = (bf16_t)v;
                    }
                }
            } else {
#pragma unroll
                for (int rg = 0; rg < 4; rg++) {
                    int gm = gmb + rg;
                    outO[(size_t)gm * DMODEL + gn] = acc[mi][ni][rg] + bv;
                }
            }
        }
    }
}

// ------------------------------------------- fused MFMA attention per (h, b, 16 q-rows)
// P (unnormalized exp'd scores) bf16 [16][2048] in swizzled LDS; mask+exp+rowsum
// fused into the QK^T epilogue. 66560 B dynamic LDS (64K S + rowpart/inv).
__global__ __launch_bounds__(256) void k_attn_f(const bf16_t* __restrict__ Qh,
                                                const bf16_t* __restrict__ Kh,
                                                const bf16_t* __restrict__ Vt,
                                                const int* __restrict__ mask,
                                                float* __restrict__ attn_out,
                                                bf16_t* __restrict__ Obf) {
    extern __shared__ char sC[];
    float* sF = (float*)sC;
    float* rowpart = (float*)(sC + 65536);  // [4 waves][16 rows]
    float* invLDS = (float*)(sC + 65792);   // [16]
    int t = threadIdx.x;
    int lane = t & 63, w = t >> 6;
    int rr = lane & 15, hq = lane >> 4;
    int bid = blockIdx.x;
    int h = bid & 7, b = (bid >> 3) & 1, qt = bid >> 4;
    int q0 = qt * 16;
    int bh = b * NHEAD + h;
    auto swzb = [](int x) { return x ^ (((x >> 12) & 7) << 4); };  // verified r6

    // Q fragments (rows q0..q0+15, K=64 -> two k-steps)
    const bf16_t* qp = Qh + ((size_t)bh * LSEQ + q0 + rr) * DKH + hq * 8;
    bf16x8 qf0 = *reinterpret_cast<const bf16x8*>(qp);
    bf16x8 qf1 = *reinterpret_cast<const bf16x8*>(qp + 32);

    // QK^T + mask + exp + partial row-sum, P -> LDS. Wave w: cols [w*512,+512)
    const bf16_t* kb = Kh + (size_t)bh * LSEQ * DKH;
    const int* mbase = mask + ((size_t)b * LSEQ + q0) * LSEQ;
    float rs[4] = {0.f, 0.f, 0.f, 0.f};
#pragma unroll 4
    for (int nt = 0; nt < 32; nt++) {
        int cb = w * 512 + nt * 16;
        int col = cb + rr;
        int mv[4];
#pragma unroll
        for (int i = 0; i < 4; i++)
            mv[i] = mbase[(size_t)(hq * 4 + i) * LSEQ + col];
        const bf16_t* kp = kb + (size_t)col * DKH + hq * 8;
        bf16x8 kf0 = *reinterpret_cast<const bf16x8*>(kp);
        bf16x8 kf1 = *reinterpret_cast<const bf16x8*>(kp + 32);
        f32x4 acc = {0.f, 0.f, 0.f, 0.f};
        acc = MFMA16(qf0, kf0, acc);
        acc = MFMA16(qf1, kf1, acc);
        // D layout: col = rr (-> score col cb+rr), row = hq*4+i. No max-sub:
        // scores O(1); masked -> 0 exactly as ref (exp(-1e18-max) flushes to 0).
#pragma unroll
        for (int i = 0; i < 4; i++) {
            float p = mv[i] ? 0.f : __expf(acc[i]);
            rs[i] += p;
            *reinterpret_cast<bf16_t*>(sC + swzb((hq * 4 + i) * 4096 + col * 2)) = (bf16_t)p;
        }
    }
    // reduce rs over the 16 rr-lanes of each hq group (contiguous lanes, width 16)
#pragma unroll
    for (int i = 0; i < 4; i++) {
        rs[i] += __shfl_xor(rs[i], 8, 16);
        rs[i] += __shfl_xor(rs[i], 4, 16);
        rs[i] += __shfl_xor(rs[i], 2, 16);
        rs[i] += __shfl_xor(rs[i], 1, 16);
    }
    if (rr == 0) {
#pragma unroll
        for (int i = 0; i < 4; i++) rowpart[w * 16 + hq * 4 + i] = rs[i];
    }
    __syncthreads();
    if (t < 16)
        invLDS[t] = 1.0f / (rowpart[t] + rowpart[16 + t] + rowpart[32 + t] + rowpart[48 + t]);
    __syncthreads();

    // attns write (f32, normalized; pattern verified r6 phase 1c)
#pragma unroll 4
    for (int i = 0; i < 32; i++) {
        int e4 = (i * 256 + t) * 4;
        int rp = e4 >> 11, cp = e4 & 2047;
        bf16x4 pv = *reinterpret_cast<bf16x4*>(sC + swzb(rp * 4096 + cp * 2));
        float inv = invLDS[rp];
        float4 ov;
        ov.x = (float)pv[0] * inv; ov.y = (float)pv[1] * inv;
        ov.z = (float)pv[2] * inv; ov.w = (float)pv[3] * inv;
        *reinterpret_cast<float4*>(attn_out +
            ((size_t)(h * 2 + b) * LSEQ + q0 + rp) * LSEQ + cp) = ov;
    }

    // PV: unnormalized P x Vt, 1/sum folded into epilogue
    float inv4[4];
#pragma unroll
    for (int i = 0; i < 4; i++) inv4[i] = invLDS[hq * 4 + i];
    const bf16_t* vb = Vt + (size_t)bh * DKH * LSEQ;
    f32x4 osum[4] = {};
#pragma unroll 4
    for (int ks = 0; ks < 16; ks++) {
        int kc = w * 512 + ks * 32 + hq * 8;
        bf16x8 pa = *reinterpret_cast<bf16x8*>(sC + swzb(rr * 4096 + kc * 2));
#pragma unroll
        for (int nt = 0; nt < 4; nt++) {
            const bf16_t* vp = vb + (size_t)(nt * 16 + rr) * LSEQ + kc;
            bf16x8 vf = *reinterpret_cast<const bf16x8*>(vp);
            osum[nt] = MFMA16(pa, vf, osum[nt]);
        }
    }
    __syncthreads();  // all S reads (attn-write + PV) done before reuse
#pragma unroll
    for (int nt = 0; nt < 4; nt++)
#pragma unroll
        for (int i = 0; i < 4; i++)
            sF[w * 1024 + (hq * 4 + i) * 64 + nt * 16 + rr] = osum[nt][i] * inv4[i];
    __syncthreads();
#pragma unroll
    for (int i = 0; i < 4; i++) {
        int e = i * 256 + t;
        int orow = e >> 6, oc = e & 63;
        float v = sF[orow * 64 + oc] + sF[1024 + orow * 64 + oc] +
                  sF[2048 + orow * 64 + oc] + sF[3072 + orow * 64 + oc];
        Obf[(((size_t)b * LSEQ + q0 + orow) * NHEAD + h) * DKH + oc] = (bf16_t)v;
    }
}

// ----------------------------------------------------------------------- launch
extern "C" void kernel_launch(void* const* d_in, const int* in_sizes, int n_in,
                              void* d_out, int out_size, void* d_ws, size_t ws_size,
                              hipStream_t stream) {
    (void)in_sizes; (void)n_in; (void)out_size; (void)ws_size;
    const float* q = (const float*)d_in[0];
    const int* mask = (const int*)d_in[3];   // int32 (verified r6)
    const float* W_qkv = (const float*)d_in[4];
    const float* b_qkv = (const float*)d_in[5];
    const float* W_proj = (const float*)d_in[6];
    const float* b_proj = (const float*)d_in[7];
    float* out = (float*)d_out;
    float* attn_out = out + (size_t)2 * LSEQ * DMODEL;  // f32 elements

    char* ws = (char*)d_ws;
    bf16_t* wqkv_t = (bf16_t*)(ws);                   // 1.5 MB
    bf16_t* wproj_t = (bf16_t*)(ws + 1572864);        // 0.5 MB
    bf16_t* Qh = (bf16_t*)(ws + 2097152);             // 4 MB
    bf16_t* Kh = (bf16_t*)(ws + 6291456);             // 4 MB
    bf16_t* Vt = (bf16_t*)(ws + 10485760);            // 4 MB
    bf16_t* Obf = (bf16_t*)(ws + 14680064);           // 4 MB  (total 18 MB)

    hipFuncSetAttribute((const void*)k_attn_f,
                        hipFuncAttributeMaxDynamicSharedMemorySize, 66560);

    k_transpose_cast<<<dim3(48, 16), dim3(32, 8), 0, stream>>>(W_qkv, wqkv_t, 512, 1536);
    k_transpose_cast<<<dim3(16, 16), dim3(32, 8), 0, stream>>>(W_proj, wproj_t, 512, 512);
    k_gemm_nt<0><<<dim3(32, 12), 256, 0, stream>>>(q, wqkv_t, b_qkv, Qh, Kh, Vt, nullptr, 512);
    k_attn_f<<<2048, 256, 66560, stream>>>(Qh, Kh, Vt, mask, attn_out, Obf);
    k_gemm_nt<1><<<dim3(32, 4), 256, 0, stream>>>(Obf, wproj_t, b_proj, nullptr, nullptr, nullptr, out, 512);
}